// Round 2
// baseline (3864.300 us; speedup 1.0000x reference)
//
#include <hip/hip_runtime.h>
#include <hip/hip_bf16.h>
#include <math.h>

// ---------------------------------------------------------------------------
// Bayesian LSTM, MI355X persistent-kernel design, round 4.
//   R3/R4 changes (sync restructure; R4 = R3 + wave0-only flag poll):
//   - fetch_add+spin barrier -> per-block generation FLAGS; wave 0 polls all
//     64 flags with one coalesced lane-load + ballot (no RMW serialization);
//     waves 1-3 park at __syncthreads (4x less poll traffic at the MALL).
//   - NO acquire fence (no buffer_inv): h lives in a WRITE-ONCE ring (slot t),
//     so consumer L2 lines can never be stale; cached loads are coherent by
//     construction (producer write-through reaches MALL before flag store).
//     If ws_size < ring size, fall back to 2-slot double buffer + sc0 sc1
//     cache-bypass loads (coherent without fences).
//   - h-GEMM A-fragments staged 32-deep up-front (128 VGPR; we run 1 wave/SIMD
//     so VGPRs are free) -> MALL/L2 latency pipelined instead of exposed.
//   - h-store issued before ys stores + x-prefetch; single vmcnt(0) before
//     flag store hides write-through latency under the shadow work.
// ---------------------------------------------------------------------------

#define T_STEPS 384
#define HID 1024
#define KTOT 1152            // HID + IN
#define KP 1160              // padded LDS row stride (bf16 elems)

// ws layout (bytes)
#define WS_WG    0ull                  // 4096*1152*2 = 9437184
#define WS_XBF   9437184ull            // 384*128*128*2 = 12582912
#define WS_BSUM  22020096ull           // 4096*4
#define WS_ACC   22036480ull           // 8 doubles
#define WS_FLAGS 22036544ull           // 4 groups * 64 * 4B = 1024
#define WS_HBUF  22037568ull           // ring: 4*385*65536 ; fallback: 4*2*65536
#define WS_ZERO_LEN 1088ull            // accd + flags
#define RING_SLOTS 385
#define RING_BYTES (WS_HBUF + 4ull * (unsigned long long)RING_SLOTS * 65536ull)

#define OUT_HN 50331648ull
#define OUT_CN 50462720ull
#define OUT_KL 50593792ull

typedef __bf16 bf16_t;
typedef bf16_t bf16x8 __attribute__((ext_vector_type(8)));
typedef float f32x4 __attribute__((ext_vector_type(4)));

__device__ __forceinline__ unsigned short f2bf(float f) {
  unsigned int u = __float_as_uint(f);
  u += 0x7fffu + ((u >> 16) & 1u);          // round-to-nearest-even
  return (unsigned short)(u >> 16);
}
__device__ __forceinline__ bf16x8 ld_bf16x8(const unsigned short* p) {
  union { uint4 u; bf16x8 v; } c;
  c.u = *(const uint4*)p;
  return c.v;
}
__device__ __forceinline__ bf16x8 u4bf(uint4 u) {
  union { uint4 u; bf16x8 v; } c;
  c.u = u;
  return c.v;
}
__device__ __forceinline__ float sigm(float x) { return 1.f / (1.f + __expf(-x)); }
__device__ __forceinline__ float tanh_fast(float x) {
  float ax = fabsf(x);
  float e = __expf(-2.f * ax);
  float t = (1.f - e) / (1.f + e);
  return copysignf(t, x);
}

// ---------------------------------------------------------------------------
__global__ __launch_bounds__(256) void prep_kernel(
    const float* __restrict__ x,
    const float* __restrict__ wim, const float* __restrict__ wir, const float* __restrict__ wie,
    const float* __restrict__ whm, const float* __restrict__ whr, const float* __restrict__ whe,
    const float* __restrict__ bim, const float* __restrict__ bir, const float* __restrict__ bie,
    const float* __restrict__ bhm, const float* __restrict__ bhr, const float* __restrict__ bhe,
    unsigned short* __restrict__ Wg, unsigned short* __restrict__ xbf,
    float* __restrict__ bsum, double* __restrict__ accd)
{
  const int NHH = 4194304, NIH = 524288, NB = 4096, NX = 6291456;
  const int NTOT = NHH + NIH + NB + NX;
  double a0=0,a1=0,a2=0,a3=0,a4=0,a5=0,a6=0,a7=0;
  int stride = gridDim.x * blockDim.x;
  for (int i = blockIdx.x * blockDim.x + threadIdx.x; i < NTOT; i += stride) {
    if (i < NHH) {                                   // w_hh -> W'[g][0:1024]
      int g = i >> 10, k = i & 1023;
      float sg = log1pf(expf(whr[i])) + 1e-5f;
      float eps = whe[i];
      float w = fmaf(sg, eps, whm[i]);
      Wg[(size_t)g * KTOT + k] = f2bf(w);
      a2 += (double)(logf(sg) + 0.5f * eps * eps);
      a3 += (double)w * (double)w;
    } else if (i < NHH + NIH) {                      // w_ih -> W'[g][1024:1152]
      int j = i - NHH;
      int g = j >> 7, k = j & 127;
      float sg = log1pf(expf(wir[j])) + 1e-5f;
      float eps = wie[j];
      float w = fmaf(sg, eps, wim[j]);
      Wg[(size_t)g * KTOT + HID + k] = f2bf(w);
      a0 += (double)(logf(sg) + 0.5f * eps * eps);
      a1 += (double)w * (double)w;
    } else if (i < NHH + NIH + NB) {                 // biases
      int k = i - NHH - NIH;
      float sg1 = log1pf(expf(bir[k])) + 1e-5f;
      float e1 = bie[k];
      float w1 = fmaf(sg1, e1, bim[k]);
      a4 += (double)(logf(sg1) + 0.5f * e1 * e1);
      a5 += (double)w1 * (double)w1;
      float sg2 = log1pf(expf(bhr[k])) + 1e-5f;
      float e2 = bhe[k];
      float w2 = fmaf(sg2, e2, bhm[k]);
      a6 += (double)(logf(sg2) + 0.5f * e2 * e2);
      a7 += (double)w2 * (double)w2;
      bsum[k] = w1 + w2;
    } else {                                         // x -> bf16
      int k = i - NHH - NIH - NB;
      xbf[k] = f2bf(x[k]);
    }
  }
  double v[8] = {a0,a1,a2,a3,a4,a5,a6,a7};
  int lane = threadIdx.x & 63, wave = threadIdx.x >> 6;
  __shared__ double red[4][8];
  #pragma unroll
  for (int q = 0; q < 8; ++q) {
    double t = v[q];
    #pragma unroll
    for (int o = 32; o > 0; o >>= 1) t += __shfl_down(t, o, 64);
    if (lane == 0) red[wave][q] = t;
  }
  __syncthreads();
  if (threadIdx.x == 0) {
    #pragma unroll
    for (int q = 0; q < 8; ++q) {
      double s = red[0][q] + red[1][q] + red[2][q] + red[3][q];
      atomicAdd(&accd[q], s);
    }
  }
}

// ---------------------------------------------------------------------------
__global__ __launch_bounds__(256, 1) void lstm_kernel(
    const unsigned short* __restrict__ Wg, const unsigned short* __restrict__ xbf,
    const float* __restrict__ bsum, unsigned short* __restrict__ hbuf,
    unsigned int* __restrict__ flags, const double* __restrict__ accd,
    float* __restrict__ out, int ring)
{
  extern __shared__ char smem[];
  unsigned short* Wl = (unsigned short*)smem;                 // 64 x KP bf16 = 148480 B
  float* gbuf = (float*)(smem + (size_t)64 * KP * 2);         // 32 x 68 f32 = 8704 B
  const int tid = threadIdx.x, gid = blockIdx.x;
  const int group = gid >> 6, idx = gid & 63, j0 = idx * 16;

  if (gid == 0 && tid == 0) {
    // KL finalize (logsumexp over tensor-level sums)
    const double L2PI = 1.8378770664093453;
    const double LN_PI = -0.28768207245178085;    // ln 0.75
    const double LN_1MPI = -1.3862943611198906;   // ln 0.25
    const double INV2S1 = 3.694528049465325;      // e^2/2
    const double INV2S2 = 601302.1420823884;      // e^14/2
    double Ns[4] = {524288.0, 4194304.0, 4096.0, 4096.0};
    double kl = 0.0;
    #pragma unroll
    for (int tq = 0; tq < 4; ++tq) {
      double post_acc = accd[2*tq], w2 = accd[2*tq+1];
      double N = Ns[tq];
      double post = -0.5 * N * L2PI - post_acc;
      double m1 = -0.5 * N * L2PI + N * 1.0 - w2 * INV2S1 + LN_PI;
      double m2 = -0.5 * N * L2PI + N * 7.0 - w2 * INV2S2 + LN_1MPI;
      double mx = fmax(m1, m2), mn = fmin(m1, m2);
      double lse = mx + log1p(exp(mn - mx));
      kl += post - lse;
    }
    out[OUT_KL] = (float)kl;
  }

  // Load this block's 64 W'-rows into LDS. LDS row r: gate p=r>>4, j=j0+(r&15)
  {
    int r = tid >> 2, c4 = tid & 3;
    int grow = ((r >> 4) << 10) + j0 + (r & 15);
    const uint4* src = (const uint4*)(Wg + (size_t)grow * KTOT);
    uint4* dst = (uint4*)(smem + (size_t)r * (KP * 2));
    #pragma unroll
    for (int j = 0; j < 36; ++j) dst[c4 + 4 * j] = src[c4 + 4 * j];
  }

  const int lane = tid & 63, wave = tid >> 6;
  const int lq = lane >> 4, ln = lane & 15;
  const int mt = wave >> 1;                       // M-tile (batch half)
  const int nt0 = (wave & 1) * 2, nt1 = nt0 + 1;  // two N-tiles (gate pairs)
  const int arow = mt * 16 + ln;                  // batch-in-group for A-frag

  const unsigned short* WB0 = Wl + (size_t)(nt0 * 16 + ln) * KP + 8 * lq;
  const unsigned short* WB1 = Wl + (size_t)(nt1 * 16 + ln) * KP + 8 * lq;
  const size_t gstr = ring ? (size_t)RING_SLOTS * 32768 : (size_t)2 * 32768;
  unsigned short* hgrp = hbuf + (size_t)group * gstr;
  const unsigned short* xrow = xbf + (size_t)(group * 32 + arow) * 128 + 8 * lq;
  unsigned int* fl = flags + group * 64;

  // nonlinearity mapping: thread -> (batch b, 2 consecutive j's)
  const int b = tid >> 3, jj0 = (tid & 7) * 2;
  const float2 bi0 = *(const float2*)&bsum[j0 + jj0];
  const float2 bi1 = *(const float2*)&bsum[1024 + j0 + jj0];
  const float2 bi2 = *(const float2*)&bsum[2048 + j0 + jj0];
  const float2 bi3 = *(const float2*)&bsum[3072 + j0 + jj0];
  float c0 = 0.f, c1 = 0.f;

  __syncthreads();

  // prologue: x-part of step 0 (h_{-1}=0 -> its GEMM is skipped at t=0)
  f32x4 acc0 = {0.f,0.f,0.f,0.f}, acc1 = {0.f,0.f,0.f,0.f};
  #pragma unroll
  for (int kk = 0; kk < 4; ++kk) {
    bf16x8 a  = ld_bf16x8(xrow + 32 * kk);
    bf16x8 b0 = ld_bf16x8(WB0 + HID + 32 * kk);
    bf16x8 b1 = ld_bf16x8(WB1 + HID + 32 * kk);
    acc0 = __builtin_amdgcn_mfma_f32_16x16x32_bf16(a, b0, acc0, 0, 0, 0);
    acc1 = __builtin_amdgcn_mfma_f32_16x16x32_bf16(a, b1, acc1, 0, 0, 0);
  }

  for (int t = 0; t < T_STEPS; ++t) {
    // h-part GEMM: gates += h_{t-1} @ W_hh^T. A-frags staged 32-deep so all
    // loads are in flight before the MFMA chain (L2/MALL latency pipelined).
    if (t > 0) {
      const int slot_r = ring ? (t - 1) : ((t & 1) ^ 1);
      const uint4* hr4 = (const uint4*)(hgrp + (size_t)slot_r * 32768 +
                                        (size_t)arow * HID + 8 * lq);
      uint4 areg[32];
      if (ring) {
        // write-once ring: cached loads are coherent (lines never stale)
        #pragma unroll
        for (int kk = 0; kk < 32; ++kk) areg[kk] = hr4[4 * kk];
      } else {
        // double-buffer fallback: bypass L1+L2, read from coherence point
        #pragma unroll
        for (int kk = 0; kk < 32; ++kk)
          asm volatile("global_load_dwordx4 %0, %1, off offset:%2 sc0 sc1"
                       : "=v"(areg[kk]) : "v"(hr4), "i"(kk * 64));
        asm volatile("s_waitcnt vmcnt(0)" ::: "memory");
        __builtin_amdgcn_sched_barrier(0);
      }
      f32x4 acc2 = {0.f,0.f,0.f,0.f}, acc3 = {0.f,0.f,0.f,0.f};
      #pragma unroll
      for (int kk = 0; kk < 32; kk += 2) {
        bf16x8 a0 = u4bf(areg[kk]);
        bf16x8 a1 = u4bf(areg[kk + 1]);
        bf16x8 b00 = ld_bf16x8(WB0 + 32 * kk);
        bf16x8 b01 = ld_bf16x8(WB1 + 32 * kk);
        bf16x8 b10 = ld_bf16x8(WB0 + 32 * (kk + 1));
        bf16x8 b11 = ld_bf16x8(WB1 + 32 * (kk + 1));
        acc0 = __builtin_amdgcn_mfma_f32_16x16x32_bf16(a0, b00, acc0, 0, 0, 0);
        acc1 = __builtin_amdgcn_mfma_f32_16x16x32_bf16(a0, b01, acc1, 0, 0, 0);
        acc2 = __builtin_amdgcn_mfma_f32_16x16x32_bf16(a1, b10, acc2, 0, 0, 0);
        acc3 = __builtin_amdgcn_mfma_f32_16x16x32_bf16(a1, b11, acc3, 0, 0, 0);
      }
      acc0 += acc2;
      acc1 += acc3;
    }
    // C layout: col=lane&15 (gate row), row=(lane>>4)*4+r (batch)
    #pragma unroll
    for (int r = 0; r < 4; ++r) {
      int m = mt * 16 + lq * 4 + r;
      gbuf[m * 68 + nt0 * 16 + ln] = acc0[r];
      gbuf[m * 68 + nt1 * 16 + ln] = acc1[r];
    }
    __syncthreads();

    // gate nonlinearity: (b, jj0), (b, jj0+1); c-state in registers
    float2 gi = *(const float2*)&gbuf[b * 68 + jj0];
    float2 gf = *(const float2*)&gbuf[b * 68 + 16 + jj0];
    float2 gg = *(const float2*)&gbuf[b * 68 + 32 + jj0];
    float2 go = *(const float2*)&gbuf[b * 68 + 48 + jj0];
    float c0n = sigm(gf.x + bi1.x) * c0 + sigm(gi.x + bi0.x) * tanh_fast(gg.x + bi2.x);
    float c1n = sigm(gf.y + bi1.y) * c1 + sigm(gi.y + bi0.y) * tanh_fast(gg.y + bi2.y);
    float h0 = sigm(go.x + bi3.x) * tanh_fast(c0n);
    float h1 = sigm(go.y + bi3.y) * tanh_fast(c1n);
    c0 = c0n; c1 = c1n;
    const bool last_t = (t == T_STEPS - 1);

    // recurrent feedback first (write-through latency hides under the shadow)
    if (!last_t) {
      const int slot_w = ring ? t : (t & 1);
      unsigned int* hw32 = (unsigned int*)(hgrp + (size_t)slot_w * 32768);
      unsigned int pk = (unsigned)f2bf(h0) | ((unsigned)f2bf(h1) << 16);
      __hip_atomic_store(&hw32[b * 512 + ((j0 + jj0) >> 1)], pk,
                         __ATOMIC_RELAXED, __HIP_MEMORY_SCOPE_AGENT);
    }

    // shadow work: ys / hn / cn stores, then x-part of step t+1
    {
      size_t bg = (size_t)(group * 32 + b);
      float2 hs = {h0, h1};
      *(float2*)&out[(size_t)t * 131072 + bg * 1024 + j0 + jj0] = hs;
      if (last_t) {
        *(float2*)&out[OUT_HN + bg * 1024 + j0 + jj0] = hs;
        float2 cs = {c0n, c1n};
        *(float2*)&out[OUT_CN + bg * 1024 + j0 + jj0] = cs;
      }
    }
    if (!last_t) {
      acc0 = (f32x4){0.f,0.f,0.f,0.f};
      acc1 = (f32x4){0.f,0.f,0.f,0.f};
      const unsigned short* xr = xrow + (size_t)(t + 1) * 16384;
      #pragma unroll
      for (int kk = 0; kk < 4; ++kk) {
        bf16x8 a  = ld_bf16x8(xr + 32 * kk);
        bf16x8 b0 = ld_bf16x8(WB0 + HID + 32 * kk);
        bf16x8 b1 = ld_bf16x8(WB1 + HID + 32 * kk);
        acc0 = __builtin_amdgcn_mfma_f32_16x16x32_bf16(a, b0, acc0, 0, 0, 0);
        acc1 = __builtin_amdgcn_mfma_f32_16x16x32_bf16(a, b1, acc1, 0, 0, 0);
      }

      // release: h stores drained before this block's flag is published
      asm volatile("s_waitcnt vmcnt(0)" ::: "memory");
      __syncthreads();
      if (tid == 0)
        __hip_atomic_store(&fl[idx], (unsigned)(t + 1),
                           __ATOMIC_RELAXED, __HIP_MEMORY_SCOPE_AGENT);

      // flag barrier: wave 0 polls all 64 flags (coalesced, no RMW);
      // waves 1-3 park at the trailing __syncthreads (4x less poll traffic)
      if (wave == 0) {
        const unsigned tgt = (unsigned)(t + 1);
        unsigned v = __hip_atomic_load(&fl[lane], __ATOMIC_RELAXED,
                                       __HIP_MEMORY_SCOPE_AGENT);
        while (__ballot(v < tgt)) {
          __builtin_amdgcn_s_sleep(1);
          v = __hip_atomic_load(&fl[lane], __ATOMIC_RELAXED,
                                __HIP_MEMORY_SCOPE_AGENT);
        }
      }
      __syncthreads();   // orders next-step h loads after the poll, all waves
    }
  }
}

// ---------------------------------------------------------------------------
extern "C" void kernel_launch(void* const* d_in, const int* in_sizes, int n_in,
                              void* d_out, int out_size, void* d_ws, size_t ws_size,
                              hipStream_t stream) {
  const float* x   = (const float*)d_in[0];
  const float* wim = (const float*)d_in[1];
  const float* wir = (const float*)d_in[2];
  const float* wie = (const float*)d_in[3];
  const float* whm = (const float*)d_in[4];
  const float* whr = (const float*)d_in[5];
  const float* whe = (const float*)d_in[6];
  const float* bim = (const float*)d_in[7];
  const float* bir = (const float*)d_in[8];
  const float* bie = (const float*)d_in[9];
  const float* bhm = (const float*)d_in[10];
  const float* bhr = (const float*)d_in[11];
  const float* bhe = (const float*)d_in[12];
  char* ws = (char*)d_ws;
  unsigned short* Wg    = (unsigned short*)(ws + WS_WG);
  unsigned short* xbf   = (unsigned short*)(ws + WS_XBF);
  float*          bsum  = (float*)(ws + WS_BSUM);
  double*         accd  = (double*)(ws + WS_ACC);
  unsigned int*   flags = (unsigned int*)(ws + WS_FLAGS);
  unsigned short* hbuf  = (unsigned short*)(ws + WS_HBUF);
  float* out = (float*)d_out;

  int ring = (ws_size >= RING_BYTES) ? 1 : 0;

  hipMemsetAsync(ws + WS_ACC, 0, WS_ZERO_LEN, stream);
  prep_kernel<<<dim3(1024), dim3(256), 0, stream>>>(
      x, wim, wir, wie, whm, whr, whe, bim, bir, bie, bhm, bhr, bhe,
      Wg, xbf, bsum, accd);

  const int SMEM = 64 * KP * 2 + 32 * 68 * 4;   // 157184 B
  hipFuncSetAttribute((const void*)lstm_kernel,
                      hipFuncAttributeMaxDynamicSharedMemorySize, SMEM);
  const unsigned short* Wg_c = Wg; const unsigned short* xbf_c = xbf;
  const float* bsum_c = bsum; const double* acc_c = accd;
  void* args[] = {(void*)&Wg_c, (void*)&xbf_c, (void*)&bsum_c,
                  (void*)&hbuf, (void*)&flags, (void*)&acc_c, (void*)&out,
                  (void*)&ring};
  hipError_t e = hipLaunchCooperativeKernel((void*)lstm_kernel, dim3(256), dim3(256),
                                            args, (unsigned)SMEM, stream);
  if (e != hipSuccess) {
    // fallback: 256 blocks / 256 CUs at 1 block/CU are co-resident in practice
    lstm_kernel<<<dim3(256), dim3(256), SMEM, stream>>>(Wg_c, xbf_c, bsum_c,
                                                        hbuf, flags, acc_c, out,
                                                        ring);
  }
}

// Round 4
// 2694.107 us; speedup vs baseline: 1.4344x; 1.4344x over previous
//
#include <hip/hip_runtime.h>
#include <hip/hip_bf16.h>
#include <math.h>

// ---------------------------------------------------------------------------
// Bayesian LSTM, MI355X persistent-kernel design, round 6 (= R5 + swizzle fix).
//   R5/R6: attack the sync-mechanism-INVARIANT costs (R2 vs R4 proved the
//   barrier flavor is not the bottleneck):
//   - areg[32] staging forced with sched_barrier(0): all 32 h-loads in
//     flight before MFMA (R4's VGPR=96 proved the compiler sank them).
//   - KPB=2304 (row stride === 0 mod 128) + XOR swizzle (slot ^= row&7 on
//     write, byte ^= (row&7)<<4 on read): uniform 8 lanes/bank-group per
//     ds_read_b128 (R5's 2320-B stride + XOR was 16-way for lq=3 quarter).
//   - packed h-ring slot layout [64 blk][32 batch][16 col]: producer store
//     is addr=tid*4 (perfectly coalesced 1KB/block); consumer A-frag reads
//     touch 2 contiguous 512B segments/instr.
//   - tail reorder: h-store -> vmcnt(0) (h only) -> syncthreads -> flag ->
//     {ys stores, x-prefetch GEMM, poll} all in the barrier shadow.
//     2 syncthreads/step (was 3); all waves poll independently.
//   - small epoch ring (P<=16 slots) + ONE acquire fence per P steps
//     (amortized buffer_inv); fence always precedes the slot re-read,
//     including across launches (t=1 is a boundary).
// ---------------------------------------------------------------------------

#define T_STEPS 384
#define HID 1024
#define KTOT 1152            // HID + IN
#define KPB 2304             // LDS row stride BYTES (=== 0 mod 128, 144 uint4)

// ws layout (bytes)
#define WS_WG    0ull                  // 4096*1152*2 = 9437184
#define WS_XBF   9437184ull            // 384*128*128*2 = 12582912
#define WS_BSUM  22020096ull           // 4096*4
#define WS_ACC   22036480ull           // 8 doubles
#define WS_FLAGS 22036544ull           // 4 groups * 64 * 4B = 1024
#define WS_HBUF  22037568ull           // 4 groups * P slots * 64KB
#define WS_ZERO_LEN 1088ull            // accd + flags

#define OUT_HN 50331648ull
#define OUT_CN 50462720ull
#define OUT_KL 50593792ull

typedef __bf16 bf16_t;
typedef bf16_t bf16x8 __attribute__((ext_vector_type(8)));
typedef float f32x4 __attribute__((ext_vector_type(4)));

__device__ __forceinline__ unsigned short f2bf(float f) {
  unsigned int u = __float_as_uint(f);
  u += 0x7fffu + ((u >> 16) & 1u);          // round-to-nearest-even
  return (unsigned short)(u >> 16);
}
__device__ __forceinline__ bf16x8 ld_bf16x8(const void* p) {
  union { uint4 u; bf16x8 v; } c;
  c.u = *(const uint4*)p;
  return c.v;
}
__device__ __forceinline__ bf16x8 u4bf(uint4 u) {
  union { uint4 u; bf16x8 v; } c;
  c.u = u;
  return c.v;
}
__device__ __forceinline__ float sigm(float x) { return 1.f / (1.f + __expf(-x)); }
__device__ __forceinline__ float tanh_fast(float x) {
  float ax = fabsf(x);
  float e = __expf(-2.f * ax);
  float t = (1.f - e) / (1.f + e);
  return copysignf(t, x);
}

// ---------------------------------------------------------------------------
__global__ __launch_bounds__(256) void prep_kernel(
    const float* __restrict__ x,
    const float* __restrict__ wim, const float* __restrict__ wir, const float* __restrict__ wie,
    const float* __restrict__ whm, const float* __restrict__ whr, const float* __restrict__ whe,
    const float* __restrict__ bim, const float* __restrict__ bir, const float* __restrict__ bie,
    const float* __restrict__ bhm, const float* __restrict__ bhr, const float* __restrict__ bhe,
    unsigned short* __restrict__ Wg, unsigned short* __restrict__ xbf,
    float* __restrict__ bsum, double* __restrict__ accd)
{
  const int NHH = 4194304, NIH = 524288, NB = 4096, NX = 6291456;
  const int NTOT = NHH + NIH + NB + NX;
  double a0=0,a1=0,a2=0,a3=0,a4=0,a5=0,a6=0,a7=0;
  int stride = gridDim.x * blockDim.x;
  for (int i = blockIdx.x * blockDim.x + threadIdx.x; i < NTOT; i += stride) {
    if (i < NHH) {                                   // w_hh -> W'[g][0:1024]
      int g = i >> 10, k = i & 1023;
      float sg = log1pf(expf(whr[i])) + 1e-5f;
      float eps = whe[i];
      float w = fmaf(sg, eps, whm[i]);
      Wg[(size_t)g * KTOT + k] = f2bf(w);
      a2 += (double)(logf(sg) + 0.5f * eps * eps);
      a3 += (double)w * (double)w;
    } else if (i < NHH + NIH) {                      // w_ih -> W'[g][1024:1152]
      int j = i - NHH;
      int g = j >> 7, k = j & 127;
      float sg = log1pf(expf(wir[j])) + 1e-5f;
      float eps = wie[j];
      float w = fmaf(sg, eps, wim[j]);
      Wg[(size_t)g * KTOT + HID + k] = f2bf(w);
      a0 += (double)(logf(sg) + 0.5f * eps * eps);
      a1 += (double)w * (double)w;
    } else if (i < NHH + NIH + NB) {                 // biases
      int k = i - NHH - NIH;
      float sg1 = log1pf(expf(bir[k])) + 1e-5f;
      float e1 = bie[k];
      float w1 = fmaf(sg1, e1, bim[k]);
      a4 += (double)(logf(sg1) + 0.5f * e1 * e1);
      a5 += (double)w1 * (double)w1;
      float sg2 = log1pf(expf(bhr[k])) + 1e-5f;
      float e2 = bhe[k];
      float w2 = fmaf(sg2, e2, bhm[k]);
      a6 += (double)(logf(sg2) + 0.5f * e2 * e2);
      a7 += (double)w2 * (double)w2;
      bsum[k] = w1 + w2;
    } else {                                         // x -> bf16
      int k = i - NHH - NIH - NB;
      xbf[k] = f2bf(x[k]);
    }
  }
  double v[8] = {a0,a1,a2,a3,a4,a5,a6,a7};
  int lane = threadIdx.x & 63, wave = threadIdx.x >> 6;
  __shared__ double red[4][8];
  #pragma unroll
  for (int q = 0; q < 8; ++q) {
    double t = v[q];
    #pragma unroll
    for (int o = 32; o > 0; o >>= 1) t += __shfl_down(t, o, 64);
    if (lane == 0) red[wave][q] = t;
  }
  __syncthreads();
  if (threadIdx.x == 0) {
    #pragma unroll
    for (int q = 0; q < 8; ++q) {
      double s = red[0][q] + red[1][q] + red[2][q] + red[3][q];
      atomicAdd(&accd[q], s);
    }
  }
}

// ---------------------------------------------------------------------------
__global__ __launch_bounds__(256, 1) void lstm_kernel(
    const unsigned short* __restrict__ Wg, const unsigned short* __restrict__ xbf,
    const float* __restrict__ bsum, unsigned short* __restrict__ hbuf,
    unsigned int* __restrict__ flags, const double* __restrict__ accd,
    float* __restrict__ out, int P)
{
  extern __shared__ char smem[];
  unsigned short* Wl = (unsigned short*)smem;                 // 64 x 2304 B = 147456 B
  float* gbuf = (float*)(smem + (size_t)64 * KPB);            // 32 x 68 f32 = 8704 B
  const int tid = threadIdx.x, gid = blockIdx.x;
  const int group = gid >> 6, idx = gid & 63, j0 = idx * 16;

  if (gid == 0 && tid == 0) {
    // KL finalize (logsumexp over tensor-level sums)
    const double L2PI = 1.8378770664093453;
    const double LN_PI = -0.28768207245178085;    // ln 0.75
    const double LN_1MPI = -1.3862943611198906;   // ln 0.25
    const double INV2S1 = 3.694528049465325;      // e^2/2
    const double INV2S2 = 601302.1420823884;      // e^14/2
    double Ns[4] = {524288.0, 4194304.0, 4096.0, 4096.0};
    double kl = 0.0;
    #pragma unroll
    for (int tq = 0; tq < 4; ++tq) {
      double post_acc = accd[2*tq], w2 = accd[2*tq+1];
      double N = Ns[tq];
      double post = -0.5 * N * L2PI - post_acc;
      double m1 = -0.5 * N * L2PI + N * 1.0 - w2 * INV2S1 + LN_PI;
      double m2 = -0.5 * N * L2PI + N * 7.0 - w2 * INV2S2 + LN_1MPI;
      double mx = fmax(m1, m2), mn = fmin(m1, m2);
      double lse = mx + log1p(exp(mn - mx));
      kl += post - lse;
    }
    out[OUT_KL] = (float)kl;
  }

  // Load this block's 64 W'-rows into LDS, XOR-swizzled: uint4 slot index
  // ^= (row&7). With row stride 2304 B (=== 0 mod 128), a ds_read_b128 of
  // 16 rows spreads uniformly 8 lanes/bank-group (conflict-free floor).
  {
    int r = tid >> 2, c4 = tid & 3;
    int grow = ((r >> 4) << 10) + j0 + (r & 15);
    const uint4* src = (const uint4*)(Wg + (size_t)grow * KTOT);
    uint4* dst = (uint4*)(smem + (size_t)r * KPB);
    int sw = r & 7;
    #pragma unroll
    for (int j = 0; j < 36; ++j) dst[(c4 + 4 * j) ^ sw] = src[c4 + 4 * j];
  }

  const int lane = tid & 63, wave = tid >> 6;
  const int lq = lane >> 4, ln = lane & 15;
  const int mt = wave >> 1;                       // M-tile (batch half)
  const int nt0 = (wave & 1) * 2, nt1 = nt0 + 1;  // two N-tiles (gate pairs)
  const int arow = mt * 16 + ln;                  // batch-in-group for A-frag

  // swizzled B-row bases (byte pointers) + per-lane XOR pattern
  const char* WB0b = (const char*)Wl + (size_t)(nt0 * 16 + ln) * KPB;
  const char* WB1b = (const char*)Wl + (size_t)(nt1 * 16 + ln) * KPB;
  const int swb = (ln & 7) << 4;                  // XOR on byte-offset bits 4-6
  const int xo = 16 * lq;

  unsigned short* hgrp = hbuf + (size_t)group * (size_t)P * 32768;
  const unsigned short* xrow = xbf + (size_t)(group * 32 + arow) * 128 + 8 * lq;
  unsigned int* fl = flags + group * 64;
  // consumer A-frag base into a packed slot [64 blk][32 b][16 col] (shorts)
  const int hbase = (lq >> 1) * 512 + arow * 16 + 8 * (lq & 1);

  // nonlinearity mapping: thread -> (batch b, 2 consecutive j's)
  const int b = tid >> 3, jj0 = (tid & 7) * 2;
  const float2 bi0 = *(const float2*)&bsum[j0 + jj0];
  const float2 bi1 = *(const float2*)&bsum[1024 + j0 + jj0];
  const float2 bi2 = *(const float2*)&bsum[2048 + j0 + jj0];
  const float2 bi3 = *(const float2*)&bsum[3072 + j0 + jj0];
  float c0 = 0.f, c1 = 0.f;

  __syncthreads();

  // prologue: x-part of step 0 (h_{-1}=0 -> h-GEMM skipped at t=0)
  f32x4 acc0 = {0.f,0.f,0.f,0.f}, acc1 = {0.f,0.f,0.f,0.f};
  #pragma unroll
  for (int kk = 0; kk < 4; ++kk) {
    bf16x8 a  = ld_bf16x8(xrow + 32 * kk);
    bf16x8 b0 = ld_bf16x8(WB0b + 2048 + ((xo + 64 * kk) ^ swb));
    bf16x8 b1 = ld_bf16x8(WB1b + 2048 + ((xo + 64 * kk) ^ swb));
    acc0 = __builtin_amdgcn_mfma_f32_16x16x32_bf16(a, b0, acc0, 0, 0, 0);
    acc1 = __builtin_amdgcn_mfma_f32_16x16x32_bf16(a, b1, acc1, 0, 0, 0);
  }

  for (int t = 0; t < T_STEPS; ++t) {
    if (t > 0) {
      // epoch boundary: one amortized acquire (cache inv) per P steps.
      // poll(t-1) already guaranteed producers' data is at the coherence
      // point; every slot re-read (period P) has exactly one fence before
      // it, including across launches (t=1 is a boundary).
      if (((t - 1) & (P - 1)) == 0) {
        __builtin_amdgcn_fence(__ATOMIC_ACQUIRE, "agent");
        __builtin_amdgcn_sched_barrier(0);
      }
      // stage ALL 32 A-frag loads before any MFMA (one latency, not four)
      const unsigned short* hr = hgrp + (size_t)((t - 1) & (P - 1)) * 32768 + hbase;
      uint4 areg[32];
      #pragma unroll
      for (int kk = 0; kk < 32; ++kk)
        areg[kk] = *(const uint4*)(hr + kk * 1024);
      __builtin_amdgcn_sched_barrier(0);

      f32x4 acc2 = {0.f,0.f,0.f,0.f}, acc3 = {0.f,0.f,0.f,0.f};
      #pragma unroll
      for (int kk = 0; kk < 32; kk += 2) {
        bf16x8 a0 = u4bf(areg[kk]);
        bf16x8 a1 = u4bf(areg[kk + 1]);
        bf16x8 b00 = ld_bf16x8(WB0b + ((xo + 64 * kk) ^ swb));
        bf16x8 b01 = ld_bf16x8(WB1b + ((xo + 64 * kk) ^ swb));
        bf16x8 b10 = ld_bf16x8(WB0b + ((xo + 64 * (kk + 1)) ^ swb));
        bf16x8 b11 = ld_bf16x8(WB1b + ((xo + 64 * (kk + 1)) ^ swb));
        acc0 = __builtin_amdgcn_mfma_f32_16x16x32_bf16(a0, b00, acc0, 0, 0, 0);
        acc1 = __builtin_amdgcn_mfma_f32_16x16x32_bf16(a0, b01, acc1, 0, 0, 0);
        acc2 = __builtin_amdgcn_mfma_f32_16x16x32_bf16(a1, b10, acc2, 0, 0, 0);
        acc3 = __builtin_amdgcn_mfma_f32_16x16x32_bf16(a1, b11, acc3, 0, 0, 0);
      }
      acc0 += acc2;
      acc1 += acc3;
    }
    // C layout: col=lane&15 (gate row), row=(lane>>4)*4+r (batch)
    #pragma unroll
    for (int r = 0; r < 4; ++r) {
      int m = mt * 16 + lq * 4 + r;
      gbuf[m * 68 + nt0 * 16 + ln] = acc0[r];
      gbuf[m * 68 + nt1 * 16 + ln] = acc1[r];
    }
    __syncthreads();

    // gate nonlinearity: (b, jj0), (b, jj0+1); c-state in registers
    float2 gi = *(const float2*)&gbuf[b * 68 + jj0];
    float2 gf = *(const float2*)&gbuf[b * 68 + 16 + jj0];
    float2 gg = *(const float2*)&gbuf[b * 68 + 32 + jj0];
    float2 go = *(const float2*)&gbuf[b * 68 + 48 + jj0];
    float c0n = sigm(gf.x + bi1.x) * c0 + sigm(gi.x + bi0.x) * tanh_fast(gg.x + bi2.x);
    float c1n = sigm(gf.y + bi1.y) * c1 + sigm(gi.y + bi0.y) * tanh_fast(gg.y + bi2.y);
    float h0 = sigm(go.x + bi3.x) * tanh_fast(c0n);
    float h1 = sigm(go.y + bi3.y) * tanh_fast(c1n);
    c0 = c0n; c1 = c1n;
    const bool last_t = (t == T_STEPS - 1);

    if (!last_t) {
      // h feedback: packed slot chunk, addr = tid*4 -> perfectly coalesced
      unsigned int* hw32 = (unsigned int*)(hgrp + (size_t)(t & (P - 1)) * 32768);
      unsigned int pk = (unsigned)f2bf(h0) | ((unsigned)f2bf(h1) << 16);
      __hip_atomic_store(&hw32[idx * 256 + tid], pk,
                         __ATOMIC_RELAXED, __HIP_MEMORY_SCOPE_AGENT);
      // drain ONLY the h store (ys/x not yet issued) -> minimal pre-flag path
      asm volatile("s_waitcnt vmcnt(0)" ::: "memory");
      __syncthreads();                           // all waves' h drained
      if (tid == 0)
        __hip_atomic_store(&fl[idx], (unsigned)(t + 1),
                           __ATOMIC_RELAXED, __HIP_MEMORY_SCOPE_AGENT);
    }

    // ---- barrier shadow: ys / hn / cn stores, then x-part of step t+1 ----
    {
      size_t bg = (size_t)(group * 32 + b);
      float2 hs = {h0, h1};
      *(float2*)&out[(size_t)t * 131072 + bg * 1024 + j0 + jj0] = hs;
      if (last_t) {
        *(float2*)&out[OUT_HN + bg * 1024 + j0 + jj0] = hs;
        float2 cs = {c0n, c1n};
        *(float2*)&out[OUT_CN + bg * 1024 + j0 + jj0] = cs;
      }
    }
    if (!last_t) {
      acc0 = (f32x4){0.f,0.f,0.f,0.f};
      acc1 = (f32x4){0.f,0.f,0.f,0.f};
      const unsigned short* xr = xrow + (size_t)(t + 1) * 16384;
      #pragma unroll
      for (int kk = 0; kk < 4; ++kk) {
        bf16x8 a  = ld_bf16x8(xr + 32 * kk);
        bf16x8 b0 = ld_bf16x8(WB0b + 2048 + ((xo + 64 * kk) ^ swb));
        bf16x8 b1 = ld_bf16x8(WB1b + 2048 + ((xo + 64 * kk) ^ swb));
        acc0 = __builtin_amdgcn_mfma_f32_16x16x32_bf16(a, b0, acc0, 0, 0, 0);
        acc1 = __builtin_amdgcn_mfma_f32_16x16x32_bf16(a, b1, acc1, 0, 0, 0);
      }

      // flag barrier: every wave polls all 64 flags (coalesced lane-load);
      // no trailing syncthreads -- gbuf reuse is protected by own flag
      // (set only after the post-vmcnt syncthreads above).
      const unsigned tgt = (unsigned)(t + 1);
      unsigned v = __hip_atomic_load(&fl[lane], __ATOMIC_RELAXED,
                                     __HIP_MEMORY_SCOPE_AGENT);
      while (__ballot(v < tgt)) {
        __builtin_amdgcn_s_sleep(1);
        v = __hip_atomic_load(&fl[lane], __ATOMIC_RELAXED,
                              __HIP_MEMORY_SCOPE_AGENT);
      }
      __builtin_amdgcn_sched_barrier(0);         // pin next h-loads below poll
    }
  }
}

// ---------------------------------------------------------------------------
extern "C" void kernel_launch(void* const* d_in, const int* in_sizes, int n_in,
                              void* d_out, int out_size, void* d_ws, size_t ws_size,
                              hipStream_t stream) {
  const float* x   = (const float*)d_in[0];
  const float* wim = (const float*)d_in[1];
  const float* wir = (const float*)d_in[2];
  const float* wie = (const float*)d_in[3];
  const float* whm = (const float*)d_in[4];
  const float* whr = (const float*)d_in[5];
  const float* whe = (const float*)d_in[6];
  const float* bim = (const float*)d_in[7];
  const float* bir = (const float*)d_in[8];
  const float* bie = (const float*)d_in[9];
  const float* bhm = (const float*)d_in[10];
  const float* bhr = (const float*)d_in[11];
  const float* bhe = (const float*)d_in[12];
  char* ws = (char*)d_ws;
  unsigned short* Wg    = (unsigned short*)(ws + WS_WG);
  unsigned short* xbf   = (unsigned short*)(ws + WS_XBF);
  float*          bsum  = (float*)(ws + WS_BSUM);
  double*         accd  = (double*)(ws + WS_ACC);
  unsigned int*   flags = (unsigned int*)(ws + WS_FLAGS);
  unsigned short* hbuf  = (unsigned short*)(ws + WS_HBUF);
  float* out = (float*)d_out;

  // epoch ring size: largest power-of-two slot count (<=16) that fits ws
  size_t avail = (ws_size > WS_HBUF) ? ws_size - WS_HBUF : (size_t)0;
  int P = 2;
  while (P < 16 && (size_t)(P * 2) * 4ull * 65536ull <= avail) P *= 2;

  hipMemsetAsync(ws + WS_ACC, 0, WS_ZERO_LEN, stream);
  prep_kernel<<<dim3(1024), dim3(256), 0, stream>>>(
      x, wim, wir, wie, whm, whr, whe, bim, bir, bie, bhm, bhr, bhe,
      Wg, xbf, bsum, accd);

  const int SMEM = 64 * KPB + 32 * 68 * 4;   // 156160 B
  hipFuncSetAttribute((const void*)lstm_kernel,
                      hipFuncAttributeMaxDynamicSharedMemorySize, SMEM);
  const unsigned short* Wg_c = Wg; const unsigned short* xbf_c = xbf;
  const float* bsum_c = bsum; const double* acc_c = accd;
  void* args[] = {(void*)&Wg_c, (void*)&xbf_c, (void*)&bsum_c,
                  (void*)&hbuf, (void*)&flags, (void*)&acc_c, (void*)&out,
                  (void*)&P};
  hipError_t e = hipLaunchCooperativeKernel((void*)lstm_kernel, dim3(256), dim3(256),
                                            args, (unsigned)SMEM, stream);
  if (e != hipSuccess) {
    // fallback: 256 blocks / 256 CUs at 1 block/CU are co-resident in practice
    lstm_kernel<<<dim3(256), dim3(256), SMEM, stream>>>(Wg_c, xbf_c, bsum_c,
                                                        hbuf, flags, acc_c, out,
                                                        P);
  }
}